// Round 11
// baseline (95.478 us; speedup 1.0000x reference)
//
#include <hip/hip_runtime.h>
#include <hip/hip_bf16.h>
#include <math.h>

#define BB   64
#define TT   1000
#define DEC  1024
#define ENCD 512
#define ATT  128
#define FILT 32
#define KSZ  31
#define PADW 15
#define BT   64    // t-tile per block
#define KC   64    // K chunk
#define XWN  96    // x-window alloc (94 used)

typedef __attribute__((ext_vector_type(8))) short bf16x8;
typedef __attribute__((ext_vector_type(4))) float f32x4;

static __device__ __forceinline__ ushort f2bf(float f) {
    union { float f; unsigned u; } v; v.f = f;
    unsigned r = (v.u + 0x7FFFu + ((v.u >> 16) & 1u)) >> 16;   // RNE
    return (ushort)r;
}

static __device__ __forceinline__ float fast_tanh(float x) {
    float e = __expf(2.f * x);
    return 1.f - 2.f * __builtin_amdgcn_rcpf(e + 1.f);
}

// async global->LDS, 16B per lane; LDS dest = wave-uniform base + lane*16
static __device__ __forceinline__ void gl2lds16(const void* g, void* l) {
    __builtin_amdgcn_global_load_lds(
        (const __attribute__((address_space(1))) unsigned*)g,
        (__attribute__((address_space(3))) unsigned*)l, 16, 0, 0);
}

// ---------------- K0: pack key_w + W2 (frag-major) AND query GEMV -------------
// blocks 0..31: key_w chunks; 32..35: W2; 36..67: query (2 batch rows each)
__global__ __launch_bounds__(256) void k_prep(const float* __restrict__ kw,
                                              const float* __restrict__ cw,
                                              const float* __restrict__ lpw,
                                              const float* __restrict__ dh,
                                              const float* __restrict__ qw,
                                              ushort* __restrict__ kwbF,
                                              float* __restrict__ q) {
    if (blockIdx.x < 32) {
        int idx = blockIdx.x * 256 + threadIdx.x;     // 0..8191
        int l  = idx & 63;
        int n  = (idx >> 6) & 7;
        int ks = (idx >> 9) & 1;
        int c  = idx >> 10;
        int a  = n * 16 + (l & 15);
        int k0 = c * 64 + ks * 32 + (l >> 4) * 8;
        ushort u[8];
        #pragma unroll
        for (int j = 0; j < 8; ++j) u[j] = f2bf(kw[a * ENCD + k0 + j]);
        *(uint4*)&kwbF[(size_t)idx * 8] = *(const uint4*)u;
    } else if (blockIdx.x < 36) {
        // W2[c][k][a] = sum_f conv_w[f][c][k] * loc_proj_w[a][f];  k==31 row = 0
        int idx = (blockIdx.x - 32) * 256 + threadIdx.x;   // 0..1023
        int l  = idx & 63;
        int n  = (idx >> 6) & 7;
        int ks = (idx >> 9) & 1;                      // conv input channel
        int a  = n * 16 + (l & 15);
        int s  = l >> 4;
        ushort u[8];
        #pragma unroll
        for (int j = 0; j < 8; ++j) {
            int k = s * 8 + j;
            float v = 0.f;
            if (k < KSZ) {
                #pragma unroll
                for (int f = 0; f < FILT; ++f)
                    v += cw[(f * 2 + ks) * KSZ + k] * lpw[a * FILT + f];
            }
            u[j] = f2bf(v);
        }
        *(uint4*)&kwbF[(size_t)(((16 + ks) * 8 + n) * 64 + l) * 8] = *(const uint4*)u;
    } else {
        int b = (blockIdx.x - 36) * 2 + (threadIdx.x >> 7);
        int a = threadIdx.x & 127;
        const float* dhb = dh + b * DEC;
        const float* qwa = qw + a * DEC;
        float s = 0.f;
        #pragma unroll 4
        for (int k = 0; k < DEC; k += 4) {
            float4 x = *(const float4*)&dhb[k];
            float4 w = *(const float4*)&qwa[k];
            s += x.x * w.x + x.y * w.y + x.z * w.z + x.w * w.w;
        }
        q[b * ATT + a] = s;
    }
}

// ---------------- K3: MFMA GEMM, K=576, dbuf + counted-vmcnt pipeline ---------
// A tile: f32 [64 rows][16 x 16B-units], unit pos swizzled c4' = c4 ^ ((row&7)<<1),
// staged via global_load_lds with pre-swizzled per-lane SOURCE (linear LDS dest).
__global__ __launch_bounds__(256) void k_energies(
    const float* __restrict__ enc, const float* __restrict__ pw,
    const float* __restrict__ pwc, const ushort* __restrict__ kwbF,
    const float* __restrict__ vw, const float* __restrict__ q,
    float* __restrict__ energ)
{
    __shared__ __align__(16) float  Ab[2][BT * 64];        // 2 x 16 KB f32 swizzled
    __shared__ __align__(16) ushort Bb[2][2 * 8 * 64 * 8]; // 2 x 16 KB frag-major linear
    __shared__ __align__(16) float  xw[2][XWN];            // 0.75 KB im2col window

    const int b   = blockIdx.x;
    const int t0  = blockIdx.y * BT;
    const int tid = threadIdx.x;
    const int w   = tid >> 6;        // 4 waves
    const int l   = tid & 63;
    const int r   = l & 15;
    const int sl  = l >> 4;
    const int row = w * 16 + r;      // wave's t-row for MFMA reads (0..63)

    const float* encb = enc + (size_t)b * TT * ENCD;

    // per-lane pre-swizzled A source pointers (issue j covers rows (j*4+w)*4 .. +3)
    const float* aSrc[4];
    #pragma unroll
    for (int j = 0; j < 4; ++j) {
        int rw  = (j * 4 + w) * 4 + (l >> 4);          // row this lane feeds
        int c4  = (l & 15) ^ ((rw & 7) << 1);          // inverse-swizzled source unit
        int tg  = t0 + rw; if (tg >= TT) tg = TT - 1;
        aSrc[j] = encb + (size_t)tg * ENCD + c4 * 4;
    }

    // ---- prologue: issue stage(0); stage x-window ----
    #pragma unroll
    for (int j = 0; j < 4; ++j)
        gl2lds16(kwbF + (size_t)(tid + j * 256) * 8,
                 &Bb[0][(size_t)(w * 64 + j * 256) * 8]);
    #pragma unroll
    for (int j = 0; j < 4; ++j)
        gl2lds16(aSrc[j], (char*)Ab[0] + (j * 4 + w) * 1024);

    for (int i = tid; i < 2 * XWN; i += 256) {
        int c  = i / XWN;
        int ii = i - c * XWN;
        int tg = t0 + ii - PADW;
        const float* src = c ? pwc : pw;
        xw[c][ii] = (ii < BT + KSZ - 1 && tg >= 0 && tg < TT) ? src[b * TT + tg] : 0.f;
    }
    asm volatile("s_waitcnt lgkmcnt(0)" ::: "memory");   // xw writes retired

    f32x4 acc[8];
    #pragma unroll
    for (int n = 0; n < 8; ++n) acc[n] = (f32x4){0.f, 0.f, 0.f, 0.f};

    #pragma unroll
    for (int c = 0; c < 9; ++c) {
        const int buf = c & 1;
        __builtin_amdgcn_s_barrier();          // compute(c-1) done -> safe to overwrite buf^1
        __builtin_amdgcn_sched_barrier(0);
        if (c < 8) {                           // issue stage(c+1) into buf^1
            #pragma unroll
            for (int j = 0; j < 4; ++j)
                gl2lds16(kwbF + (size_t)(c + 1) * 8192 + (size_t)(tid + j * 256) * 8,
                         &Bb[buf ^ 1][(size_t)(w * 64 + j * 256) * 8]);
            if (c < 7) {
                #pragma unroll
                for (int j = 0; j < 4; ++j)
                    gl2lds16(aSrc[j] + (c + 1) * KC, (char*)Ab[buf ^ 1] + (j * 4 + w) * 1024);
            }
        }
        // wait ONLY stage(c)'s loads; stage(c+1)'s remain in flight (T4)
        if (c < 7)       asm volatile("s_waitcnt vmcnt(8)" ::: "memory");
        else if (c == 7) asm volatile("s_waitcnt vmcnt(4)" ::: "memory");
        else             asm volatile("s_waitcnt vmcnt(0)" ::: "memory");
        __builtin_amdgcn_sched_barrier(0);
        __builtin_amdgcn_s_barrier();          // all waves' stage(c) landed

        #pragma unroll
        for (int ks = 0; ks < 2; ++ks) {
            bf16x8 af;
            if (c < 8) {
                int s   = ks * 4 + sl;
                int c4p = (2 * s) ^ ((row & 7) << 1);
                const char* ap = (const char*)Ab[buf] + row * 256 + c4p * 16;
                float4 alo = *(const float4*)ap;
                float4 ahi = *(const float4*)(ap + 16);
                ushort u[8] = { f2bf(alo.x), f2bf(alo.y), f2bf(alo.z), f2bf(alo.w),
                                f2bf(ahi.x), f2bf(ahi.y), f2bf(ahi.z), f2bf(ahi.w) };
                af = *(const bf16x8*)u;
            } else {
                // im2col fragment: A[t][ks*32 + sl*8 + j] = xw[ks][t + sl*8 + j]
                const float* xp = &xw[ks][row + sl * 8];
                ushort u[8] = { f2bf(xp[0]), f2bf(xp[1]), f2bf(xp[2]), f2bf(xp[3]),
                                f2bf(xp[4]), f2bf(xp[5]), f2bf(xp[6]), f2bf(xp[7]) };
                af = *(const bf16x8*)u;
            }
            #pragma unroll
            for (int n = 0; n < 8; ++n) {
                bf16x8 bv = *(const bf16x8*)&Bb[buf][(size_t)((ks * 8 + n) * 64 + l) * 8];
                acc[n] = __builtin_amdgcn_mfma_f32_16x16x32_bf16(af, bv, acc[n], 0, 0, 0);
            }
        }
    }

    // ---- epilogue: + query, tanh, v-dot, reduce over a (16 lanes) ----
    const float* qb = q + b * ATT;
    float pe[4];
    #pragma unroll
    for (int rr = 0; rr < 4; ++rr) pe[rr] = 0.f;
    #pragma unroll
    for (int n = 0; n < 8; ++n) {
        int a = n * 16 + r;
        float vvn = vw[a];
        float qvn = qb[a];
        #pragma unroll
        for (int rr = 0; rr < 4; ++rr)
            pe[rr] += vvn * fast_tanh(acc[n][rr] + qvn);
    }
    #pragma unroll
    for (int m = 1; m < 16; m <<= 1) {
        #pragma unroll
        for (int rr = 0; rr < 4; ++rr)
            pe[rr] += __shfl_xor(pe[rr], m, 64);
    }
    if (r == 0) {
        #pragma unroll
        for (int rr = 0; rr < 4; ++rr) {
            int t = t0 + w * 16 + sl * 4 + rr;
            if (t < TT) energ[b * TT + t] = pe[rr];
        }
    }
}

// ---------------- K4: softmax over T per batch row ----------------------------
__global__ __launch_bounds__(256) void k_softmax(const float* __restrict__ energ,
                                                 const unsigned char* __restrict__ mask,
                                                 float* __restrict__ wout) {
    int b = blockIdx.x, tid = threadIdx.x;
    __shared__ float sred[8];
    const float* eb = energ + b * TT;
    const unsigned char* mb = mask + b * TT;
    float m = -INFINITY;
    for (int t = tid; t < TT; t += 256) {
        float e = mb[t] ? -INFINITY : eb[t];
        m = fmaxf(m, e);
    }
    #pragma unroll
    for (int off = 32; off; off >>= 1) m = fmaxf(m, __shfl_xor(m, off, 64));
    if ((tid & 63) == 0) sred[tid >> 6] = m;
    __syncthreads();
    m = fmaxf(fmaxf(sred[0], sred[1]), fmaxf(sred[2], sred[3]));
    float s = 0.f;
    for (int t = tid; t < TT; t += 256) {
        float e = mb[t] ? -INFINITY : eb[t];
        s += expf(e - m);
    }
    #pragma unroll
    for (int off = 32; off; off >>= 1) s += __shfl_xor(s, off, 64);
    if ((tid & 63) == 0) sred[4 + (tid >> 6)] = s;
    __syncthreads();
    s = sred[4] + sred[5] + sred[6] + sred[7];
    float inv = 1.f / s;
    float* wb = wout + b * TT;
    for (int t = tid; t < TT; t += 256) {
        float e = mb[t] ? -INFINITY : eb[t];
        wb[t] = expf(e - m) * inv;
    }
}

// ---------------- K5: partial context (8 t-chunks of 125, float4 loads) -------
#define TCH 125
__global__ __launch_bounds__(512) void k_ctx_partial(const float* __restrict__ enc,
                                                     const float* __restrict__ w,
                                                     float* __restrict__ partial) {
    int b = blockIdx.x, c = blockIdx.y;
    int e4 = threadIdx.x & 127;      // float4 column
    int g  = threadIdx.x >> 7;       // 0..3 t-stripe
    __shared__ float sw[TCH];
    int tstart = c * TCH;
    if (threadIdx.x < TCH) sw[threadIdx.x] = w[b * TT + tstart + threadIdx.x];
    __syncthreads();
    const float* p = enc + ((size_t)b * TT + tstart) * ENCD;
    float4 acc = make_float4(0.f, 0.f, 0.f, 0.f);
    for (int t = g; t < TCH; t += 4) {
        float s = sw[t];
        float4 v = *(const float4*)(p + (size_t)t * ENCD + e4 * 4);
        acc.x += s * v.x; acc.y += s * v.y; acc.z += s * v.z; acc.w += s * v.w;
    }
    *(float4*)&partial[(size_t)(((b * 8 + c) * 4 + g)) * ENCD + e4 * 4] = acc;
}

// ---------------- K6: reduce 32 partials -> context ---------------------------
__global__ __launch_bounds__(512) void k_ctx_reduce(const float* __restrict__ partial,
                                                    float* __restrict__ ctx) {
    int b = blockIdx.x, e = threadIdx.x;
    float s = 0.f;
    #pragma unroll
    for (int i = 0; i < 32; ++i) s += partial[(size_t)(b * 32 + i) * ENCD + e];
    ctx[b * ENCD + e] = s;
}

// ---------------- launcher ----------------------------------------------------
extern "C" void kernel_launch(void* const* d_in, const int* in_sizes, int n_in,
                              void* d_out, int out_size, void* d_ws, size_t ws_size,
                              hipStream_t stream) {
    const float* dh   = (const float*)d_in[0];
    const float* enc  = (const float*)d_in[1];
    const float* pw   = (const float*)d_in[2];
    const float* pwc  = (const float*)d_in[3];
    const unsigned char* mask = (const unsigned char*)d_in[4];
    const float* cw   = (const float*)d_in[5];
    const float* lpw  = (const float*)d_in[6];
    const float* qw   = (const float*)d_in[7];
    const float* kw   = (const float*)d_in[8];
    const float* vw   = (const float*)d_in[9];

    float* out_ctx = (float*)d_out;                 // (64, 512)
    float* out_w   = out_ctx + BB * ENCD;           // (64, 1000)

    float* wsf   = (float*)d_ws;
    float*  q     = wsf;                             // 8192 f
    float*  energ = wsf + 8192;                      // 64000 f
    float*  part  = wsf + 8192 + 64000;              // 64*32*512 f
    ushort* kwbF  = (ushort*)(wsf + 8192 + 64000 + 64 * 32 * 512);  // 73728 bf16

    k_prep    <<<dim3(68),     dim3(256), 0, stream>>>(kw, cw, lpw, dh, qw, kwbF, q);
    k_energies<<<dim3(BB, 16), dim3(256), 0, stream>>>(enc, pw, pwc, kwbF, vw, q, energ);
    k_softmax <<<dim3(BB),     dim3(256), 0, stream>>>(energ, mask, out_w);
    k_ctx_partial<<<dim3(BB, 8), dim3(512), 0, stream>>>(enc, out_w, part);
    k_ctx_reduce <<<dim3(BB),    dim3(512), 0, stream>>>(part, out_ctx);
}

// Round 12
// 75.671 us; speedup vs baseline: 1.2617x; 1.2617x over previous
//
#include <hip/hip_runtime.h>
#include <hip/hip_bf16.h>
#include <math.h>

#define BB   64
#define TT   1000
#define DEC  1024
#define ENCD 512
#define ATT  128
#define FILT 32
#define KSZ  31
#define PADW 15
#define BT   64    // t-tile per block
#define KC   64    // K chunk
#define XWN  96    // x-window alloc (94 used)

typedef __attribute__((ext_vector_type(8))) short bf16x8;
typedef __attribute__((ext_vector_type(4))) float f32x4;

static __device__ __forceinline__ ushort f2bf(float f) {
    union { float f; unsigned u; } v; v.f = f;
    unsigned r = (v.u + 0x7FFFu + ((v.u >> 16) & 1u)) >> 16;   // RNE
    return (ushort)r;
}

static __device__ __forceinline__ bf16x8 cvt8(float4 lo, float4 hi) {
    union { __hip_bfloat162 h[4]; bf16x8 v; } u;
    u.h[0] = __float22bfloat162_rn(make_float2(lo.x, lo.y));
    u.h[1] = __float22bfloat162_rn(make_float2(lo.z, lo.w));
    u.h[2] = __float22bfloat162_rn(make_float2(hi.x, hi.y));
    u.h[3] = __float22bfloat162_rn(make_float2(hi.z, hi.w));
    return u.v;
}

static __device__ __forceinline__ float fast_tanh(float x) {
    float e = __expf(2.f * x);
    return 1.f - 2.f * __builtin_amdgcn_rcpf(e + 1.f);
}

// async global->LDS, 16B per lane; LDS dest = wave-uniform base + lane*16
static __device__ __forceinline__ void gl2lds16(const void* g, void* l) {
    __builtin_amdgcn_global_load_lds(
        (const __attribute__((address_space(1))) unsigned*)g,
        (__attribute__((address_space(3))) unsigned*)l, 16, 0, 0);
}

// ---------------- K0: pack key_w + W2 (frag-major), M = sum|v|, query GEMV ----
// frag element index = (((c*2+ks)*8 + n)*64 + lane)*8 + j
//   a = n*16 + (lane&15),  k = c*64 + ks*32 + (lane>>4)*8 + j
__global__ __launch_bounds__(256) void k_prep(const float* __restrict__ kw,
                                              const float* __restrict__ cw,
                                              const float* __restrict__ lpw,
                                              const float* __restrict__ dh,
                                              const float* __restrict__ qw,
                                              const float* __restrict__ vw,
                                              ushort* __restrict__ kwbF,
                                              float* __restrict__ q,
                                              float* __restrict__ Mbuf) {
    __shared__ float qred[128];
    if (blockIdx.x < 32) {
        int idx = blockIdx.x * 256 + threadIdx.x;     // 0..8191
        int l  = idx & 63;
        int n  = (idx >> 6) & 7;
        int ks = (idx >> 9) & 1;
        int c  = idx >> 10;
        int a  = n * 16 + (l & 15);
        int k0 = c * 64 + ks * 32 + (l >> 4) * 8;
        ushort u[8];
        #pragma unroll
        for (int j = 0; j < 8; ++j) u[j] = f2bf(kw[a * ENCD + k0 + j]);
        *(uint4*)&kwbF[(size_t)idx * 8] = *(const uint4*)u;
    } else if (blockIdx.x < 36) {
        // W2[c][k][a] = sum_f conv_w[f][c][k] * loc_proj_w[a][f];  k==31 row = 0
        int idx = (blockIdx.x - 32) * 256 + threadIdx.x;   // 0..1023
        int l  = idx & 63;
        int n  = (idx >> 6) & 7;
        int ks = (idx >> 9) & 1;                      // conv input channel
        int a  = n * 16 + (l & 15);
        int s  = l >> 4;
        ushort u[8];
        #pragma unroll
        for (int j = 0; j < 8; ++j) {
            int k = s * 8 + j;
            float v = 0.f;
            if (k < KSZ) {
                #pragma unroll
                for (int f = 0; f < FILT; ++f)
                    v += cw[(f * 2 + ks) * KSZ + k] * lpw[a * FILT + f];
            }
            u[j] = f2bf(v);
        }
        *(uint4*)&kwbF[(size_t)(((16 + ks) * 8 + n) * 64 + l) * 8] = *(const uint4*)u;
    } else if (blockIdx.x == 36) {
        if (threadIdx.x < 64) {
            float m0 = fabsf(vw[threadIdx.x]) + fabsf(vw[threadIdx.x + 64]);
            #pragma unroll
            for (int off = 1; off < 64; off <<= 1) m0 += __shfl_xor(m0, off, 64);
            if (threadIdx.x == 0) Mbuf[0] = m0;
        }
    } else {
        // query GEMV, one block per b, 128 a x 2-way k-split
        int b  = blockIdx.x - 37;
        int a  = threadIdx.x & 127;
        int kh = threadIdx.x >> 7;
        const float* dhb = dh + b * DEC + kh * 512;
        const float* qwa = qw + a * DEC + kh * 512;
        float s = 0.f;
        #pragma unroll 4
        for (int k = 0; k < 512; k += 4) {
            float4 x = *(const float4*)&dhb[k];
            float4 w = *(const float4*)&qwa[k];
            s += x.x * w.x + x.y * w.y + x.z * w.z + x.w * w.w;
        }
        if (kh == 1) qred[a] = s;
        __syncthreads();
        if (kh == 0) q[b * ATT + a] = s + qred[a];
    }
}

// ---------------- K3: MFMA GEMM K=576 -> expE = exp(energy - M) ---------------
// A tile: f32 [64 rows][16 units of 16B], unit' = unit ^ (row&15) (bank-uniform),
// staged via global_load_lds with pre-swizzled per-lane SOURCE (linear LDS dest).
// B: fragment-major kwbF, loaded straight to registers (coalesced dwordx4).
__global__ __launch_bounds__(256) void k_energies(
    const float* __restrict__ enc, const float* __restrict__ pw,
    const float* __restrict__ pwc, const unsigned char* __restrict__ mask,
    const ushort* __restrict__ kwbF, const float* __restrict__ vw,
    const float* __restrict__ q, const float* __restrict__ Mbuf,
    float* __restrict__ expE)
{
    __shared__ __align__(16) float Ab[BT * 64];     // 16 KB f32, unit-swizzled
    __shared__ __align__(16) float xw[2][XWN];      // 0.75 KB im2col window
    __shared__ float pehalf[2][BT];                 // cross-wave a-combine

    const int b   = blockIdx.x;
    const int t0  = blockIdx.y * BT;
    const int tid = threadIdx.x;
    const int w   = tid >> 6;        // 4 waves
    const int l   = tid & 63;
    const int r   = l & 15;
    const int sl  = l >> 4;
    const int wt  = w & 1;           // t-half (32 rows)
    const int wa  = w >> 1;          // a-half (64 cols)

    const float* encb = enc + (size_t)b * TT * ENCD;

    // per-lane pre-swizzled A source pointers; issue j covers rows (j*4+w)*4..+3
    // LDS[row][u] = enc[row][u ^ (row&15)]
    const int c4src = (l & 15) ^ (w * 4 + (l >> 4));
    const float* aSrc[4];
    #pragma unroll
    for (int j = 0; j < 4; ++j) {
        int rw  = (j * 4 + w) * 4 + (l >> 4);
        int tg  = t0 + rw; if (tg >= TT) tg = TT - 1;
        aSrc[j] = encb + (size_t)tg * ENCD + c4src * 4;
    }

    // ---- stage x-window (zero-padded) ----
    for (int i = tid; i < 2 * XWN; i += 256) {
        int c  = i / XWN;
        int ii = i - c * XWN;
        int tg = t0 + ii - PADW;
        const float* src = c ? pwc : pw;
        xw[c][ii] = (ii < BT + KSZ - 1 && tg >= 0 && tg < TT) ? src[b * TT + tg] : 0.f;
    }

    f32x4 acc[2][4];   // [row-group i][n-frag nn]
    #pragma unroll
    for (int i = 0; i < 2; ++i)
        #pragma unroll
        for (int n = 0; n < 4; ++n) acc[i][n] = (f32x4){0.f, 0.f, 0.f, 0.f};

    for (int c = 0; c < 9; ++c) {
        __syncthreads();                     // WAR: previous compute done with Ab
        if (c < 8) {
            #pragma unroll
            for (int j = 0; j < 4; ++j)
                gl2lds16(aSrc[j] + c * KC, (char*)Ab + (j * 4 + w) * 1024);
        }
        // B fragments for this chunk -> registers (coalesced, L2-hot)
        uint4 bfr[2][4];
        #pragma unroll
        for (int ks = 0; ks < 2; ++ks)
            #pragma unroll
            for (int nn = 0; nn < 4; ++nn)
                bfr[ks][nn] = *(const uint4*)&kwbF[(size_t)(((c * 2 + ks) * 8 + wa * 4 + nn) * 64 + l) * 8];
        __syncthreads();                     // drains vmcnt(0): Ab + bfr ready

        #pragma unroll
        for (int ks = 0; ks < 2; ++ks) {
            const int s2 = 2 * (ks * 4 + sl);
            bf16x8 af[2];
            #pragma unroll
            for (int i = 0; i < 2; ++i) {
                int row = wt * 32 + i * 16 + r;
                if (c < 8) {
                    const char* base = (const char*)Ab + row * 256;
                    float4 alo = *(const float4*)(base + ((s2 ^ r) << 4));
                    float4 ahi = *(const float4*)(base + (((s2 | 1) ^ r) << 4));
                    af[i] = cvt8(alo, ahi);
                } else {
                    const float* xp = &xw[ks][row + sl * 8];
                    float4 alo = make_float4(xp[0], xp[1], xp[2], xp[3]);
                    float4 ahi = make_float4(xp[4], xp[5], xp[6], xp[7]);
                    af[i] = cvt8(alo, ahi);
                }
            }
            #pragma unroll
            for (int i = 0; i < 2; ++i)
                #pragma unroll
                for (int nn = 0; nn < 4; ++nn)
                    acc[i][nn] = __builtin_amdgcn_mfma_f32_16x16x32_bf16(
                        af[i], *(const bf16x8*)&bfr[ks][nn], acc[i][nn], 0, 0, 0);
        }
    }

    // ---- epilogue: + query, tanh, v-dot over this wave's a-half ----
    const float* qb = q + b * ATT;
    const float M = Mbuf[0];
    float pe[2][4];
    #pragma unroll
    for (int i = 0; i < 2; ++i)
        #pragma unroll
        for (int rr = 0; rr < 4; ++rr) pe[i][rr] = 0.f;
    #pragma unroll
    for (int nn = 0; nn < 4; ++nn) {
        int a = wa * 64 + nn * 16 + r;
        float vvn = vw[a];
        float qvn = qb[a];
        #pragma unroll
        for (int i = 0; i < 2; ++i)
            #pragma unroll
            for (int rr = 0; rr < 4; ++rr)
                pe[i][rr] += vvn * fast_tanh(acc[i][nn][rr] + qvn);
    }
    #pragma unroll
    for (int m = 1; m < 16; m <<= 1)
        #pragma unroll
        for (int i = 0; i < 2; ++i)
            #pragma unroll
            for (int rr = 0; rr < 4; ++rr)
                pe[i][rr] += __shfl_xor(pe[i][rr], m, 64);
    if (r == 0) {
        #pragma unroll
        for (int i = 0; i < 2; ++i)
            #pragma unroll
            for (int rr = 0; rr < 4; ++rr)
                pehalf[wa][wt * 32 + i * 16 + sl * 4 + rr] = pe[i][rr];
    }
    __syncthreads();
    if (tid < BT) {
        int t = t0 + tid;
        if (t < TT) {
            float e = pehalf[0][tid] + pehalf[1][tid];
            float v = mask[b * TT + t] ? 0.f : __expf(e - M);
            expE[b * TT + t] = v;
        }
    }
}

// ---------------- K5: partial context + partial sum (8 t-chunks of 125) -------
#define TCH 125
__global__ __launch_bounds__(512) void k_ctx_partial(const float* __restrict__ enc,
                                                     const float* __restrict__ expE,
                                                     float* __restrict__ pctx,
                                                     float* __restrict__ ps) {
    int b = blockIdx.x, c = blockIdx.y;
    int e4 = threadIdx.x & 127;      // float4 column
    int g  = threadIdx.x >> 7;       // 0..3 t-stripe
    __shared__ float sw[TCH];
    int tstart = c * TCH;
    if (threadIdx.x < TCH) sw[threadIdx.x] = expE[b * TT + tstart + threadIdx.x];
    __syncthreads();
    const float* p = enc + ((size_t)b * TT + tstart) * ENCD;
    float4 acc = make_float4(0.f, 0.f, 0.f, 0.f);
    float sacc = 0.f;
    for (int t = g; t < TCH; t += 4) {
        float s = sw[t];
        float4 v = *(const float4*)(p + (size_t)t * ENCD + e4 * 4);
        acc.x += s * v.x; acc.y += s * v.y; acc.z += s * v.z; acc.w += s * v.w;
        sacc += s;
    }
    int slot = (b * 8 + c) * 4 + g;
    *(float4*)&pctx[(size_t)slot * ENCD + e4 * 4] = acc;
    if (e4 == 0) ps[slot] = sacc;
}

// ---------------- K6: reduce partials -> context + attention weights ----------
__global__ __launch_bounds__(512) void k_ctx_reduce(const float* __restrict__ pctx,
                                                    const float* __restrict__ ps,
                                                    const float* __restrict__ expE,
                                                    float* __restrict__ ctx,
                                                    float* __restrict__ wout) {
    int b = blockIdx.x, tid = threadIdx.x;
    __shared__ float sps[32];
    if (tid < 32) sps[tid] = ps[b * 32 + tid];
    __syncthreads();
    float s = 0.f;
    #pragma unroll
    for (int i = 0; i < 32; ++i) s += sps[i];
    float inv = 1.f / s;
    float a = 0.f;
    #pragma unroll
    for (int i = 0; i < 32; ++i) a += pctx[(size_t)(b * 32 + i) * ENCD + tid];
    ctx[b * ENCD + tid] = a * inv;
    for (int t = tid; t < TT; t += 512)
        wout[b * TT + t] = expE[b * TT + t] * inv;
}

// ---------------- launcher ----------------------------------------------------
extern "C" void kernel_launch(void* const* d_in, const int* in_sizes, int n_in,
                              void* d_out, int out_size, void* d_ws, size_t ws_size,
                              hipStream_t stream) {
    const float* dh   = (const float*)d_in[0];
    const float* enc  = (const float*)d_in[1];
    const float* pw   = (const float*)d_in[2];
    const float* pwc  = (const float*)d_in[3];
    const unsigned char* mask = (const unsigned char*)d_in[4];
    const float* cw   = (const float*)d_in[5];
    const float* lpw  = (const float*)d_in[6];
    const float* qw   = (const float*)d_in[7];
    const float* kw   = (const float*)d_in[8];
    const float* vw   = (const float*)d_in[9];

    float* out_ctx = (float*)d_out;                 // (64, 512)
    float* out_w   = out_ctx + BB * ENCD;           // (64, 1000)

    float* wsf    = (float*)d_ws;
    float*  q     = wsf;                             // 8192
    float*  expE  = wsf + 8192;                      // 64000
    float*  ps    = wsf + 8192 + 64000;              // 2048
    float*  pctx  = wsf + 8192 + 64000 + 2048;       // 65536
    ushort* kwbF  = (ushort*)(wsf + 8192 + 64000 + 2048 + 65536);  // 73728 bf16
    float*  Mbuf  = wsf + 8192 + 64000 + 2048 + 65536 + 36864;     // 1

    k_prep    <<<dim3(101),    dim3(256), 0, stream>>>(kw, cw, lpw, dh, qw, vw, kwbF, q, Mbuf);
    k_energies<<<dim3(BB, 16), dim3(256), 0, stream>>>(enc, pw, pwc, mask, kwbF, vw, q, Mbuf, expE);
    k_ctx_partial<<<dim3(BB, 8), dim3(512), 0, stream>>>(enc, expE, pctx, ps);
    k_ctx_reduce <<<dim3(BB),    dim3(512), 0, stream>>>(pctx, ps, expE, out_ctx, out_w);
}

// Round 13
// 67.250 us; speedup vs baseline: 1.4198x; 1.1252x over previous
//
#include <hip/hip_runtime.h>
#include <hip/hip_bf16.h>
#include <math.h>

#define BB   64
#define TT   1000
#define DEC  1024
#define ENCD 512
#define ATT  128
#define FILT 32
#define KSZ  31
#define PADW 15
#define BT   64    // t-tile per block
#define KC   64    // K chunk
#define XWN  96    // x-window alloc (94 used)

typedef __attribute__((ext_vector_type(8))) short bf16x8;
typedef __attribute__((ext_vector_type(4))) float f32x4;

static __device__ __forceinline__ ushort f2bf(float f) {
    union { float f; unsigned u; } v; v.f = f;
    unsigned r = (v.u + 0x7FFFu + ((v.u >> 16) & 1u)) >> 16;   // RNE
    return (ushort)r;
}

static __device__ __forceinline__ bf16x8 cvt8(float4 lo, float4 hi) {
    union { __hip_bfloat162 h[4]; bf16x8 v; } u;
    u.h[0] = __float22bfloat162_rn(make_float2(lo.x, lo.y));
    u.h[1] = __float22bfloat162_rn(make_float2(lo.z, lo.w));
    u.h[2] = __float22bfloat162_rn(make_float2(hi.x, hi.y));
    u.h[3] = __float22bfloat162_rn(make_float2(hi.z, hi.w));
    return u.v;
}

static __device__ __forceinline__ float fast_tanh(float x) {
    float e = __expf(2.f * x);
    return 1.f - 2.f * __builtin_amdgcn_rcpf(e + 1.f);
}

// async global->LDS, 16B per lane; LDS dest = wave-uniform base + lane*16
static __device__ __forceinline__ void gl2lds16(const void* g, void* l) {
    __builtin_amdgcn_global_load_lds(
        (const __attribute__((address_space(1))) unsigned*)g,
        (__attribute__((address_space(3))) unsigned*)l, 16, 0, 0);
}

// ---------------- K0: pack key_w + W2 (frag-major), M = sum|v|, query GEMV ----
__global__ __launch_bounds__(256) void k_prep(const float* __restrict__ kw,
                                              const float* __restrict__ cw,
                                              const float* __restrict__ lpw,
                                              const float* __restrict__ dh,
                                              const float* __restrict__ qw,
                                              const float* __restrict__ vw,
                                              ushort* __restrict__ kwbF,
                                              float* __restrict__ q,
                                              float* __restrict__ Mbuf) {
    __shared__ float qred[128];
    if (blockIdx.x < 32) {
        int idx = blockIdx.x * 256 + threadIdx.x;     // 0..8191
        int l  = idx & 63;
        int n  = (idx >> 6) & 7;
        int ks = (idx >> 9) & 1;
        int c  = idx >> 10;
        int a  = n * 16 + (l & 15);
        int k0 = c * 64 + ks * 32 + (l >> 4) * 8;
        ushort u[8];
        #pragma unroll
        for (int j = 0; j < 8; ++j) u[j] = f2bf(kw[a * ENCD + k0 + j]);
        *(uint4*)&kwbF[(size_t)idx * 8] = *(const uint4*)u;
    } else if (blockIdx.x < 36) {
        // W2[c][k][a] = sum_f conv_w[f][c][k] * loc_proj_w[a][f];  k==31 row = 0
        int idx = (blockIdx.x - 32) * 256 + threadIdx.x;   // 0..1023
        int l  = idx & 63;
        int n  = (idx >> 6) & 7;
        int ks = (idx >> 9) & 1;                      // conv input channel
        int a  = n * 16 + (l & 15);
        int s  = l >> 4;
        ushort u[8];
        #pragma unroll
        for (int j = 0; j < 8; ++j) {
            int k = s * 8 + j;
            float v = 0.f;
            if (k < KSZ) {
                #pragma unroll
                for (int f = 0; f < FILT; ++f)
                    v += cw[(f * 2 + ks) * KSZ + k] * lpw[a * FILT + f];
            }
            u[j] = f2bf(v);
        }
        *(uint4*)&kwbF[(size_t)(((16 + ks) * 8 + n) * 64 + l) * 8] = *(const uint4*)u;
    } else if (blockIdx.x == 36) {
        if (threadIdx.x < 64) {
            float m0 = fabsf(vw[threadIdx.x]) + fabsf(vw[threadIdx.x + 64]);
            #pragma unroll
            for (int off = 1; off < 64; off <<= 1) m0 += __shfl_xor(m0, off, 64);
            if (threadIdx.x == 0) Mbuf[0] = m0;
        }
    } else {
        // query GEMV, one block per b, 128 a x 2-way k-split
        int b  = blockIdx.x - 37;
        int a  = threadIdx.x & 127;
        int kh = threadIdx.x >> 7;
        const float* dhb = dh + b * DEC + kh * 512;
        const float* qwa = qw + a * DEC + kh * 512;
        float s = 0.f;
        #pragma unroll 4
        for (int k = 0; k < 512; k += 4) {
            float4 x = *(const float4*)&dhb[k];
            float4 w = *(const float4*)&qwa[k];
            s += x.x * w.x + x.y * w.y + x.z * w.z + x.w * w.w;
        }
        if (kh == 1) qred[a] = s;
        __syncthreads();
        if (kh == 0) q[b * ATT + a] = s + qred[a];
    }
}

// ------- K3: MFMA GEMM K=576 -> expE, FUSED with per-tile context partial -----
// A tile: f32 [64 rows][16 units of 16B], unit' = unit ^ (row&15) (bank-uniform),
// A double-buffered via global_load_lds + counted vmcnt (never 0 in loop).
// B: fragment-major kwbF -> named register double-buffers (implicit dbuf).
__global__ __launch_bounds__(256) void k_energies(
    const float* __restrict__ enc, const float* __restrict__ pw,
    const float* __restrict__ pwc, const unsigned char* __restrict__ mask,
    const ushort* __restrict__ kwbF, const float* __restrict__ vw,
    const float* __restrict__ q, const float* __restrict__ Mbuf,
    float* __restrict__ expE, float* __restrict__ pctx,
    float* __restrict__ ps)
{
    __shared__ __align__(16) float Ab[2][BT * 64];  // 2 x 16 KB f32, unit-swizzled
    __shared__ __align__(16) float xw[2][XWN];      // 0.75 KB im2col window
    __shared__ float pehalf[2][BT];                 // cross-wave a-combine
    __shared__ float sExp[BT];

    const int b    = blockIdx.x;
    const int tile = blockIdx.y;
    const int t0   = tile * BT;
    const int tid  = threadIdx.x;
    const int w    = tid >> 6;       // 4 waves
    const int l    = tid & 63;
    const int r    = l & 15;
    const int sl   = l >> 4;
    const int wt   = w & 1;          // t-half (32 rows)
    const int wa   = w >> 1;         // a-half (64 cols)

    const float* encb = enc + (size_t)b * TT * ENCD;

    // per-lane pre-swizzled A source pointers; LDS[row][u] = enc[row][u ^ (row&15)]
    const int c4src = (l & 15) ^ (w * 4 + (l >> 4));
    const float* aSrc[4];
    #pragma unroll
    for (int j = 0; j < 4; ++j) {
        int rw  = (j * 4 + w) * 4 + (l >> 4);
        int tg  = t0 + rw; if (tg >= TT) tg = TT - 1;
        aSrc[j] = encb + (size_t)tg * ENCD + c4src * 4;
    }

    // ---- stage x-window (zero-padded) ----
    for (int i = tid; i < 2 * XWN; i += 256) {
        int c  = i / XWN;
        int ii = i - c * XWN;
        int tg = t0 + ii - PADW;
        const float* src = c ? pwc : pw;
        xw[c][ii] = (ii < BT + KSZ - 1 && tg >= 0 && tg < TT) ? src[b * TT + tg] : 0.f;
    }

    uint4 bfr0[2][4], bfr1[2][4];    // named B double-buffers (rule #20: static idx)
    auto loadB = [&](uint4 (&dst)[2][4], int c) {
        #pragma unroll
        for (int ks = 0; ks < 2; ++ks)
            #pragma unroll
            for (int nn = 0; nn < 4; ++nn)
                dst[ks][nn] = *(const uint4*)&kwbF[(size_t)(((c * 2 + ks) * 8 + wa * 4 + nn) * 64 + l) * 8];
    };
    auto issueA = [&](int c, int buf) {
        #pragma unroll
        for (int j = 0; j < 4; ++j)
            gl2lds16(aSrc[j] + c * KC, (char*)Ab[buf] + (j * 4 + w) * 1024);
    };

    f32x4 acc[2][4];
    #pragma unroll
    for (int i = 0; i < 2; ++i)
        #pragma unroll
        for (int n = 0; n < 4; ++n) acc[i][n] = (f32x4){0.f, 0.f, 0.f, 0.f};

    auto compute = [&](int c, const uint4 (&bfr)[2][4]) {
        #pragma unroll
        for (int ks = 0; ks < 2; ++ks) {
            const int s2 = 2 * (ks * 4 + sl);
            bf16x8 af[2];
            #pragma unroll
            for (int i = 0; i < 2; ++i) {
                int row = wt * 32 + i * 16 + r;
                if (c < 8) {
                    const char* base = (const char*)Ab[c & 1] + row * 256;
                    float4 alo = *(const float4*)(base + ((s2 ^ r) << 4));
                    float4 ahi = *(const float4*)(base + (((s2 | 1) ^ r) << 4));
                    af[i] = cvt8(alo, ahi);
                } else {
                    const float* xp = &xw[ks][row + sl * 8];
                    float4 alo = make_float4(xp[0], xp[1], xp[2], xp[3]);
                    float4 ahi = make_float4(xp[4], xp[5], xp[6], xp[7]);
                    af[i] = cvt8(alo, ahi);
                }
            }
            #pragma unroll
            for (int i = 0; i < 2; ++i)
                #pragma unroll
                for (int nn = 0; nn < 4; ++nn)
                    acc[i][nn] = __builtin_amdgcn_mfma_f32_16x16x32_bf16(
                        af[i], *(const bf16x8*)&bfr[ks][nn], acc[i][nn], 0, 0, 0);
        }
    };

    // ---- prologue: 2-deep prefetch ----
    issueA(0, 0); loadB(bfr0, 0);
    issueA(1, 1); loadB(bfr1, 1);
    asm volatile("s_waitcnt vmcnt(12) lgkmcnt(0)" ::: "memory");  // chunk0 landed; xw visible
    __builtin_amdgcn_sched_barrier(0);
    __builtin_amdgcn_s_barrier();

    // ---- main loop: counted vmcnt, never drained to 0 until tail ----
    #pragma unroll
    for (int c = 0; c < 9; ++c) {
        if (c & 1) compute(c, bfr1); else compute(c, bfr0);
        if (c == 8) break;
        __builtin_amdgcn_s_barrier();        // all waves done reading Ab[c&1]
        __builtin_amdgcn_sched_barrier(0);
        if (c + 2 <= 8) {
            if (c + 2 <= 7) issueA(c + 2, c & 1);
            if (c & 1) loadB(bfr1, c + 2); else loadB(bfr0, c + 2);
        }
        if (c <= 4)      asm volatile("s_waitcnt vmcnt(12)" ::: "memory");
        else if (c == 5) asm volatile("s_waitcnt vmcnt(12)" ::: "memory");
        else if (c == 6) asm volatile("s_waitcnt vmcnt(8)"  ::: "memory");
        else             asm volatile("s_waitcnt vmcnt(0)"  ::: "memory");
        __builtin_amdgcn_sched_barrier(0);
        __builtin_amdgcn_s_barrier();        // stage(c+1) visible to all waves
    }

    // ---- epilogue: + query, tanh, v-dot over this wave's a-half ----
    const float* qb = q + b * ATT;
    const float M = Mbuf[0];
    float pe[2][4];
    #pragma unroll
    for (int i = 0; i < 2; ++i)
        #pragma unroll
        for (int rr = 0; rr < 4; ++rr) pe[i][rr] = 0.f;
    #pragma unroll
    for (int nn = 0; nn < 4; ++nn) {
        int a = wa * 64 + nn * 16 + r;
        float vvn = vw[a];
        float qvn = qb[a];
        #pragma unroll
        for (int i = 0; i < 2; ++i)
            #pragma unroll
            for (int rr = 0; rr < 4; ++rr)
                pe[i][rr] += vvn * fast_tanh(acc[i][nn][rr] + qvn);
    }
    #pragma unroll
    for (int m = 1; m < 16; m <<= 1)
        #pragma unroll
        for (int i = 0; i < 2; ++i)
            #pragma unroll
            for (int rr = 0; rr < 4; ++rr)
                pe[i][rr] += __shfl_xor(pe[i][rr], m, 64);
    if (r == 0) {
        #pragma unroll
        for (int i = 0; i < 2; ++i)
            #pragma unroll
            for (int rr = 0; rr < 4; ++rr)
                pehalf[wa][wt * 32 + i * 16 + sl * 4 + rr] = pe[i][rr];
    }
    __syncthreads();
    if (tid < BT) {
        int t = t0 + tid;
        float e = pehalf[0][tid] + pehalf[1][tid];
        float v = 0.f;
        if (t < TT && !mask[b * TT + t]) v = __expf(e - M);
        if (t < TT) expE[b * TT + t] = v;
        sExp[tid] = v;
        float sv = v;
        #pragma unroll
        for (int off = 1; off < 64; off <<= 1) sv += __shfl_xor(sv, off, 64);
        if (tid == 0) ps[b * 16 + tile] = sv;
    }
    __syncthreads();

    // ---- fused context partial: enc rows are L2-hot from the GEMM pass ----
    const int tmax = (TT - t0 < BT) ? (TT - t0) : BT;
    float2 cacc = make_float2(0.f, 0.f);
    const float* pbase = encb + (size_t)t0 * ENCD + tid * 2;
    for (int t = 0; t < tmax; ++t) {
        float s = sExp[t];
        float2 v = *(const float2*)(pbase + (size_t)t * ENCD);
        cacc.x += s * v.x; cacc.y += s * v.y;
    }
    *(float2*)&pctx[(size_t)(b * 16 + tile) * ENCD + tid * 2] = cacc;
}

// ---------------- K6: reduce 16 partials -> context + attention weights -------
__global__ __launch_bounds__(512) void k_ctx_reduce(const float* __restrict__ pctx,
                                                    const float* __restrict__ ps,
                                                    const float* __restrict__ expE,
                                                    float* __restrict__ ctx,
                                                    float* __restrict__ wout) {
    int b = blockIdx.x, tid = threadIdx.x;
    __shared__ float sps[16];
    if (tid < 16) sps[tid] = ps[b * 16 + tid];
    __syncthreads();
    float s = 0.f;
    #pragma unroll
    for (int i = 0; i < 16; ++i) s += sps[i];
    float inv = 1.f / s;
    float a = 0.f;
    #pragma unroll
    for (int i = 0; i < 16; ++i) a += pctx[(size_t)(b * 16 + i) * ENCD + tid];
    ctx[b * ENCD + tid] = a * inv;
    for (int t = tid; t < TT; t += 512)
        wout[b * TT + t] = expE[b * TT + t] * inv;
}

// ---------------- launcher ----------------------------------------------------
extern "C" void kernel_launch(void* const* d_in, const int* in_sizes, int n_in,
                              void* d_out, int out_size, void* d_ws, size_t ws_size,
                              hipStream_t stream) {
    const float* dh   = (const float*)d_in[0];
    const float* enc  = (const float*)d_in[1];
    const float* pw   = (const float*)d_in[2];
    const float* pwc  = (const float*)d_in[3];
    const unsigned char* mask = (const unsigned char*)d_in[4];
    const float* cw   = (const float*)d_in[5];
    const float* lpw  = (const float*)d_in[6];
    const float* qw   = (const float*)d_in[7];
    const float* kw   = (const float*)d_in[8];
    const float* vw   = (const float*)d_in[9];

    float* out_ctx = (float*)d_out;                 // (64, 512)
    float* out_w   = out_ctx + BB * ENCD;           // (64, 1000)

    float* wsf    = (float*)d_ws;
    float*  q     = wsf;                             // 8192
    float*  expE  = wsf + 8192;                      // 64000
    float*  ps    = wsf + 8192 + 64000;              // 1024
    float*  pctx  = wsf + 8192 + 64000 + 1024;       // 64*16*512 = 524288
    ushort* kwbF  = (ushort*)(wsf + 8192 + 64000 + 1024 + 524288);  // 73728 bf16
    float*  Mbuf  = wsf + 8192 + 64000 + 1024 + 524288 + 36864;     // 1

    k_prep    <<<dim3(101),    dim3(256), 0, stream>>>(kw, cw, lpw, dh, qw, vw, kwbF, q, Mbuf);
    k_energies<<<dim3(BB, 16), dim3(256), 0, stream>>>(enc, pw, pwc, mask, kwbF, vw, q, Mbuf, expE, pctx, ps);
    k_ctx_reduce <<<dim3(BB),  dim3(512), 0, stream>>>(pctx, ps, expE, out_ctx, out_w);
}